// Round 1
// baseline (424.120 us; speedup 1.0000x reference)
//
#include <hip/hip_runtime.h>

// DEChannelPool: 6 soft-morphology branches + per-channel BN + 1x1 conv + BN + ReLU.
// Trick 1: exp(beta*(w±x)) = exp(beta*w)*exp(±beta*x): 2 exps per input pixel (shifted
//          by M for fp32 range), reused across all taps/branches.
// Trick 2: BN+conv fold to alpha*log2(S) + const; const cancels in the final scalar BN
//          (final BN is shift- AND scale-invariant per uniform offsets; ln2 folded into alpha).
// This revision: register-rotating stencil (no colv staging array -> no remat storm),
// 8-row strips on 64x32 tiles, literal ds_read offsets off one base pointer.

#define BETA 15.0f
#define MSHIFT 25.0f
#define INV_BETA (1.0f/15.0f)
#define LN2 0.6931471805599453f
#define EPSB 1e-5f
#define Hn 192
#define Wn 192
#define HWn (192*192)
#define N1 (8*192*192)
#define HALO 3
#define TILE_W 32
#define TILE_H 64
#define TDW 38              // TILE_W + 2*HALO
#define TDH 70              // TILE_H + 2*HALO
#define TSTR 39             // TDW + 1 pad (float2 units)
#define NLOAD (TDH*TDW)     // 2660
#define NTW 6               // 192/32
#define NTILES 18           // (192/64) * (192/32)
#define SFLOOR 1e-37f

// workspace layout (float offsets)
#define WS_SUM   0
#define WS_SQS   384
#define WS_SCAL  768
#define WS_ALPHA 772
#define WS_WG    1156
#define WS_YE    4612
#define WS_YD    (4612 + 294912)
#define WS_TOTAL (4612 + 2*294912)

__global__ void k_wexp(const float* __restrict__ we,
                       const float* __restrict__ wd,
                       float* __restrict__ wg) {
    int idx = blockIdx.x * 256 + threadIdx.x;
    if (idx >= 3456) return;
    int kb = idx / 576;            // 0..5 (0-2 erosion, 3-5 dilation)
    int rem = idx - kb * 576;      // c*9 + tap
    float w = (kb < 3) ? we[kb * 576 + rem] : wd[(kb - 3) * 576 + rem];
    wg[idx] = __expf(BETA * w);
}

// Fill the 70x38 halo tile of (exp(-bx-M), exp(bx-M)) pairs. Incremental div-mod.
__device__ __forceinline__ void load_tile(const float* __restrict__ xp,
                                          float2* __restrict__ E,
                                          int h0, int w0, int tid) {
    const float em0 = __expf(-MSHIFT);
    int r = tid / TDW;
    int cc = tid - r * TDW;
    for (int l = tid; l < NLOAD; l += 256) {
        int gh = h0 - HALO + r, gw = w0 - HALO + cc;
        float2 e;
        if ((unsigned)gh < (unsigned)Hn && (unsigned)gw < (unsigned)Wn) {
            float bx = BETA * xp[gh * Wn + gw];
            e.x = __expf(-bx - MSHIFT);   // erosion term
            e.y = __expf( bx - MSHIFT);   // dilation term
        } else { e.x = em0; e.y = em0; }  // zero padding -> x=0
        E[r * TSTR + cc] = e;
        r += 6; cc += 28;                 // 256 = 6*38 + 28
        if (cc >= TDW) { cc -= TDW; ++r; }
    }
}

// Register-rotating stencil: sweep input rows, each float2 read feeds up to 3 output
// accumulators directly. All indices literal after unroll (D is a template param),
// so SE/SD stay in VGPRs and every ds_read is base + literal offset.
template<int D>
__device__ __forceinline__ void morph_branch(const float2* __restrict__ E,
                                             int py0, int px,
                                             const float* __restrict__ wgE,
                                             const float* __restrict__ wgD,
                                             float* __restrict__ SE,
                                             float* __restrict__ SD) {
    float WE[9], WD[9];
#pragma unroll
    for (int k2 = 0; k2 < 9; ++k2) { WE[k2] = wgE[k2]; WD[k2] = wgD[k2]; }
#pragma unroll
    for (int k = 0; k < 8; ++k) { SE[k] = 0.f; SD[k] = 0.f; }
    const float2* base = E + (py0 - D + HALO) * TSTR + (px - D);
#pragma unroll
    for (int r = 0; r < 8 + 2 * D; ++r) {
        float2 va = base[r * TSTR];
        float2 vb = base[r * TSTR + D];
        float2 vc = base[r * TSTR + 2 * D];
#pragma unroll
        for (int i = 0; i < 3; ++i) {
            int k = r - i * D;            // output row fed by input row r via weight-row i
            if (k >= 0 && k < 8) {
                SE[k] = fmaf(WE[i*3+0], va.x, SE[k]);
                SE[k] = fmaf(WE[i*3+1], vb.x, SE[k]);
                SE[k] = fmaf(WE[i*3+2], vc.x, SE[k]);
                SD[k] = fmaf(WD[i*3+0], va.y, SD[k]);
                SD[k] = fmaf(WD[i*3+1], vb.y, SD[k]);
                SD[k] = fmaf(WD[i*3+2], vc.y, SD[k]);
            }
        }
    }
}

__global__ __launch_bounds__(256) void k_morph_stats(
    const float* __restrict__ x, const float* __restrict__ wg,
    float* __restrict__ sum, float* __restrict__ sqs) {
    __shared__ float2 E[TDH * TSTR];
    __shared__ float redS[4][6], redQ[4][6];
    const int tid = threadIdx.x;
    const int p = blockIdx.y;            // b*64 + c
    const int c = p & 63;
    const int t = blockIdx.x;
    const int h0 = (t / NTW) * TILE_H, w0 = (t % NTW) * TILE_W;

    load_tile(x + (size_t)p * HWn, E, h0, w0, tid);
    __syncthreads();

    const int px = (tid & 31) + HALO;
    const int py0 = (tid >> 5) * 8;      // 8-row vertical strip per thread
    float s[6] = {0,0,0,0,0,0}, q[6] = {0,0,0,0,0,0};

#define DO_BRANCH_STATS(D, BR) { \
    float SE[8], SD[8]; \
    morph_branch<D>(E, py0, px, wg + ((BR)*64 + c)*9, wg + (((BR)+3)*64 + c)*9, SE, SD); \
    _Pragma("unroll") \
    for (int k = 0; k < 8; ++k) { \
        float me = fmaf(__log2f(fmaxf(SE[k], SFLOOR)), -LN2*INV_BETA, -MSHIFT*INV_BETA); \
        float md = fmaf(__log2f(fmaxf(SD[k], SFLOOR)),  LN2*INV_BETA,  MSHIFT*INV_BETA); \
        s[BR] += me; q[BR] = fmaf(me, me, q[BR]); \
        s[(BR)+3] += md; q[(BR)+3] = fmaf(md, md, q[(BR)+3]); \
    } }

    DO_BRANCH_STATS(1, 0)
    DO_BRANCH_STATS(2, 1)
    DO_BRANCH_STATS(3, 2)

    const int lane = tid & 63, wv = tid >> 6;
#pragma unroll
    for (int v = 0; v < 6; ++v) {
        float a = s[v], b2 = q[v];
#pragma unroll
        for (int off = 32; off; off >>= 1) {
            a  += __shfl_down(a, off, 64);
            b2 += __shfl_down(b2, off, 64);
        }
        if (lane == 0) { redS[wv][v] = a; redQ[wv][v] = b2; }
    }
    __syncthreads();
    if (tid < 6)
        atomicAdd(&sum[tid * 64 + c], redS[0][tid] + redS[1][tid] + redS[2][tid] + redS[3][tid]);
    else if (tid < 12) {
        int v = tid - 6;
        atomicAdd(&sqs[v * 64 + c], redQ[0][v] + redQ[1][v] + redQ[2][v] + redQ[3][v]);
    }
}

__global__ void k_alpha(const float* __restrict__ sum, const float* __restrict__ sqs,
                        const float* __restrict__ bn_ge,
                        const float* __restrict__ bn_gd,
                        const float* __restrict__ conve,
                        const float* __restrict__ convd,
                        float* __restrict__ alpha) {
    int tid = threadIdx.x;
    if (tid >= 384) return;
    float mean = sum[tid] * (1.0f / N1);
    float var  = sqs[tid] * (1.0f / N1) - mean * mean;
    float inv  = rsqrtf(fmaxf(var, 0.f) + EPSB);
    float g, cw, sgn;
    if (tid < 192) { g = bn_ge[tid];       cw = conve[tid];       sgn = -1.f; }
    else           { g = bn_gd[tid - 192]; cw = convd[tid - 192]; sgn =  1.f; }
    // ln2 folded so pass 2 can use __log2f directly
    alpha[tid] = sgn * cw * g * inv * INV_BETA * LN2;
}

__global__ __launch_bounds__(256) void k_reduce_c(
    const float* __restrict__ x, const float* __restrict__ wg,
    const float* __restrict__ alpha, float* __restrict__ ye, float* __restrict__ yd) {
    __shared__ float2 E[TDH * TSTR];
    const int tid = threadIdx.x;
    const int t = blockIdx.x;             // 18 tiles
    const int bz = blockIdx.y;            // b*8 + chunk
    const int b = bz >> 3, chunk = bz & 7;
    const int h0 = (t / NTW) * TILE_H, w0 = (t % NTW) * TILE_W;
    const int px = (tid & 31) + HALO;
    const int py0 = (tid >> 5) * 8;
    float accE[8] = {0,0,0,0,0,0,0,0}, accD[8] = {0,0,0,0,0,0,0,0};

    for (int ci = 0; ci < 8; ++ci) {
        const int c = chunk * 8 + ci;
        __syncthreads();
        load_tile(x + (size_t)(b * 64 + c) * HWn, E, h0, w0, tid);
        __syncthreads();

#define DO_BRANCH_ACC(D, BR) { \
        float SE[8], SD[8]; \
        morph_branch<D>(E, py0, px, wg + ((BR)*64 + c)*9, wg + (((BR)+3)*64 + c)*9, SE, SD); \
        const float aE = alpha[(BR)*64 + c]; \
        const float aD = alpha[((BR)+3)*64 + c]; \
        _Pragma("unroll") \
        for (int k = 0; k < 8; ++k) { \
            accE[k] = fmaf(aE, __log2f(fmaxf(SE[k], SFLOOR)), accE[k]); \
            accD[k] = fmaf(aD, __log2f(fmaxf(SD[k], SFLOOR)), accD[k]); \
        } }

        DO_BRANCH_ACC(1, 0)
        DO_BRANCH_ACC(2, 1)
        DO_BRANCH_ACC(3, 2)
    }
#pragma unroll
    for (int k = 0; k < 8; ++k) {
        int idx = b * HWn + (h0 + py0 + k) * Wn + (w0 + px - HALO);
        atomicAdd(&ye[idx], accE[k]);
        atomicAdd(&yd[idx], accD[k]);
    }
}

__global__ __launch_bounds__(256) void k_fstats(const float* __restrict__ ye,
                                                const float* __restrict__ yd,
                                                float* __restrict__ scal) {
    int i = blockIdx.x * 256 + threadIdx.x;
    float a = ye[i], b = yd[i];
    float v[4] = {a, a * a, b, b * b};
    __shared__ float red[4][4];
    int lane = threadIdx.x & 63, wv = threadIdx.x >> 6;
#pragma unroll
    for (int k = 0; k < 4; ++k) {
        float tv = v[k];
#pragma unroll
        for (int off = 32; off; off >>= 1) tv += __shfl_down(tv, off, 64);
        if (lane == 0) red[wv][k] = tv;
    }
    __syncthreads();
    if (threadIdx.x < 4)
        atomicAdd(&scal[threadIdx.x],
                  red[0][threadIdx.x] + red[1][threadIdx.x] + red[2][threadIdx.x] + red[3][threadIdx.x]);
}

__global__ __launch_bounds__(256) void k_final(
    const float* __restrict__ ye, const float* __restrict__ yd,
    const float* __restrict__ scal,
    const float* __restrict__ g_e, const float* __restrict__ b_e,
    const float* __restrict__ g_d, const float* __restrict__ b_d,
    float* __restrict__ out) {
    int i = blockIdx.x * 256 + threadIdx.x;  // < 294912
    float me_ = scal[0] * (1.0f / N1);
    float ve  = scal[1] * (1.0f / N1) - me_ * me_;
    float ie  = rsqrtf(fmaxf(ve, 0.f) + EPSB);
    float md_ = scal[2] * (1.0f / N1);
    float vd  = scal[3] * (1.0f / N1) - md_ * md_;
    float idv = rsqrtf(fmaxf(vd, 0.f) + EPSB);
    float ge = g_e[0], be = b_e[0];
    float gd = g_d[0], bd = b_d[0];
    int b = i / HWn, rem = i - b * HWn;
    float oe = fmaxf(ge * (ye[i] - me_) * ie + be, 0.f);
    float od = fmaxf(gd * (yd[i] - md_) * idv + bd, 0.f);
    out[(size_t)(b * 2) * HWn + rem]     = oe;
    out[(size_t)(b * 2 + 1) * HWn + rem] = od;
}

extern "C" void kernel_launch(void* const* d_in, const int* in_sizes, int n_in,
                              void* d_out, int out_size, void* d_ws, size_t ws_size,
                              hipStream_t stream) {
    const float* x     = (const float*)d_in[0];
    const float* we    = (const float*)d_in[1];
    const float* wd    = (const float*)d_in[2];
    const float* bn_ge = (const float*)d_in[3];
    const float* bn_gd = (const float*)d_in[5];
    const float* conve = (const float*)d_in[7];
    const float* convd = (const float*)d_in[8];
    const float* g_e   = (const float*)d_in[9];
    const float* b_e   = (const float*)d_in[10];
    const float* g_d   = (const float*)d_in[11];
    const float* b_d   = (const float*)d_in[12];
    float* ws = (float*)d_ws;

    hipMemsetAsync(d_ws, 0, (size_t)WS_TOTAL * sizeof(float), stream);
    hipLaunchKernelGGL(k_wexp, dim3(14), dim3(256), 0, stream, we, wd, ws + WS_WG);
    hipLaunchKernelGGL(k_morph_stats, dim3(NTILES, 512), dim3(256), 0, stream,
                       x, ws + WS_WG, ws + WS_SUM, ws + WS_SQS);
    hipLaunchKernelGGL(k_alpha, dim3(1), dim3(384), 0, stream,
                       ws + WS_SUM, ws + WS_SQS, bn_ge, bn_gd, conve, convd, ws + WS_ALPHA);
    hipLaunchKernelGGL(k_reduce_c, dim3(NTILES, 64), dim3(256), 0, stream,
                       x, ws + WS_WG, ws + WS_ALPHA, ws + WS_YE, ws + WS_YD);
    hipLaunchKernelGGL(k_fstats, dim3(1152), dim3(256), 0, stream,
                       ws + WS_YE, ws + WS_YD, ws + WS_SCAL);
    hipLaunchKernelGGL(k_final, dim3(1152), dim3(256), 0, stream,
                       ws + WS_YE, ws + WS_YD, ws + WS_SCAL, g_e, b_e, g_d, b_d,
                       (float*)d_out);
}

// Round 2
// 396.577 us; speedup vs baseline: 1.0695x; 1.0695x over previous
//
#include <hip/hip_runtime.h>

// DEChannelPool: 6 soft-morphology branches + per-channel BN + 1x1 conv + BN + ReLU.
// Trick 1: exp(beta*(w±x)) = exp(beta*w)*exp(±beta*x): 2 exps per input pixel (shifted
//          by M for fp32 range), reused across all taps/branches.
// Trick 2: BN+conv fold to alpha*log2(S) + const; const cancels in the final scalar BN.
// R2: occupancy fix. Split E/D sweeps (8 acc + 9 W live instead of 16+18), separate
//     EX/EY LDS planes (b32 reads, consecutive banks), per-branch stat reduction,
//     __launch_bounds__(256,7) to pin 7 blocks/CU (LDS-limited).

#define BETA 15.0f
#define MSHIFT 25.0f
#define INV_BETA (1.0f/15.0f)
#define LN2 0.6931471805599453f
#define EPSB 1e-5f
#define Hn 192
#define Wn 192
#define HWn (192*192)
#define N1 (8*192*192)
#define HALO 3
#define TILE_W 32
#define TILE_H 64
#define TDW 38              // TILE_W + 2*HALO
#define TDH 70              // TILE_H + 2*HALO
#define TSTRf 39            // TDW + 1 pad (floats)
#define PLANE (TDH*TSTRf)   // 2730 floats
#define NLOAD (TDH*TDW)     // 2660
#define NTW 6               // 192/32
#define NTILES 18           // (192/64) * (192/32)
#define SFLOOR 1e-37f

// workspace layout (float offsets)
#define WS_SUM   0
#define WS_SQS   384
#define WS_SCAL  768
#define WS_ALPHA 772
#define WS_WG    1156
#define WS_YE    4612
#define WS_YD    (4612 + 294912)
#define WS_TOTAL (4612 + 2*294912)

__global__ void k_wexp(const float* __restrict__ we,
                       const float* __restrict__ wd,
                       float* __restrict__ wg) {
    int idx = blockIdx.x * 256 + threadIdx.x;
    if (idx >= 3456) return;
    int kb = idx / 576;            // 0..5 (0-2 erosion, 3-5 dilation)
    int rem = idx - kb * 576;      // c*9 + tap
    float w = (kb < 3) ? we[kb * 576 + rem] : wd[(kb - 3) * 576 + rem];
    wg[idx] = __expf(BETA * w);
}

// Fill the 70x38 halo tile: EX = exp(-bx-M) (erosion), EY = exp(bx-M) (dilation).
__device__ __forceinline__ void load_tile(const float* __restrict__ xp,
                                          float* __restrict__ EX,
                                          float* __restrict__ EY,
                                          int h0, int w0, int tid) {
    const float em0 = __expf(-MSHIFT);
    int r = tid / TDW;
    int cc = tid - r * TDW;
    for (int l = tid; l < NLOAD; l += 256) {
        int gh = h0 - HALO + r, gw = w0 - HALO + cc;
        float ex, ey;
        if ((unsigned)gh < (unsigned)Hn && (unsigned)gw < (unsigned)Wn) {
            float bx = BETA * xp[gh * Wn + gw];
            ex = __expf(-bx - MSHIFT);
            ey = __expf( bx - MSHIFT);
        } else { ex = em0; ey = em0; }    // zero padding -> x=0
        int idx = r * TSTRf + cc;
        EX[idx] = ex;
        EY[idx] = ey;
        r += 6; cc += 28;                 // 256 = 6*38 + 28
        if (cc >= TDW) { cc -= TDW; ++r; }
    }
}

// Register-rotating stencil over ONE plane (one morphology side). Each b32 read
// feeds up to 3 of the 8 output accumulators. All offsets literal after unroll.
template<int D>
__device__ __forceinline__ void sweep(const float* __restrict__ P,
                                      int py0, int px,
                                      const float* __restrict__ wgp,
                                      float* __restrict__ S) {
    float W[9];
#pragma unroll
    for (int k2 = 0; k2 < 9; ++k2) W[k2] = wgp[k2];
#pragma unroll
    for (int k = 0; k < 8; ++k) S[k] = 0.f;
    const float* base = P + (py0 - D + HALO) * TSTRf + (px - D);
#pragma unroll
    for (int r = 0; r < 8 + 2 * D; ++r) {
        float va = base[r * TSTRf];
        float vb = base[r * TSTRf + D];
        float vc = base[r * TSTRf + 2 * D];
#pragma unroll
        for (int i = 0; i < 3; ++i) {
            int k = r - i * D;            // output row fed by input row r via weight-row i
            if (k >= 0 && k < 8) {
                S[k] = fmaf(W[i*3+0], va, S[k]);
                S[k] = fmaf(W[i*3+1], vb, S[k]);
                S[k] = fmaf(W[i*3+2], vc, S[k]);
            }
        }
    }
}

__device__ __forceinline__ void red2(float a, float b2, int lane, float* rs, float* rq) {
#pragma unroll
    for (int off = 32; off; off >>= 1) {
        a  += __shfl_down(a, off, 64);
        b2 += __shfl_down(b2, off, 64);
    }
    if (lane == 0) { *rs = a; *rq = b2; }
}

__global__ __launch_bounds__(256, 7) void k_morph_stats(
    const float* __restrict__ x, const float* __restrict__ wg,
    float* __restrict__ sum, float* __restrict__ sqs) {
    __shared__ float EX[PLANE], EY[PLANE];
    __shared__ float redS[4][6], redQ[4][6];
    const int tid = threadIdx.x;
    const int p = blockIdx.y;            // b*64 + c
    const int c = p & 63;
    const int t = blockIdx.x;
    const int h0 = (t / NTW) * TILE_H, w0 = (t % NTW) * TILE_W;

    load_tile(x + (size_t)p * HWn, EX, EY, h0, w0, tid);
    __syncthreads();

    const int px = (tid & 31) + HALO;
    const int py0 = (tid >> 5) * 8;      // 8-row vertical strip per thread
    const int lane = tid & 63, wv = tid >> 6;

#define DO_SIDE_STATS(D, BR, PL, SGN, SLOT) { \
    float S[8]; \
    sweep<D>(PL, py0, px, wg + (SLOT)*576 + c*9, S); \
    float sv = 0.f, qv = 0.f; \
    _Pragma("unroll") \
    for (int k = 0; k < 8; ++k) { \
        float m = fmaf(__log2f(fmaxf(S[k], SFLOOR)), (SGN)*LN2*INV_BETA, (SGN)*MSHIFT*INV_BETA); \
        sv += m; qv = fmaf(m, m, qv); \
    } \
    red2(sv, qv, lane, &redS[wv][SLOT], &redQ[wv][SLOT]); }

    DO_SIDE_STATS(1, 0, EX, -1.f, 0)
    DO_SIDE_STATS(1, 0, EY,  1.f, 3)
    DO_SIDE_STATS(2, 1, EX, -1.f, 1)
    DO_SIDE_STATS(2, 1, EY,  1.f, 4)
    DO_SIDE_STATS(3, 2, EX, -1.f, 2)
    DO_SIDE_STATS(3, 2, EY,  1.f, 5)

    __syncthreads();
    if (tid < 6)
        atomicAdd(&sum[tid * 64 + c], redS[0][tid] + redS[1][tid] + redS[2][tid] + redS[3][tid]);
    else if (tid < 12) {
        int v = tid - 6;
        atomicAdd(&sqs[v * 64 + c], redQ[0][v] + redQ[1][v] + redQ[2][v] + redQ[3][v]);
    }
}

__global__ void k_alpha(const float* __restrict__ sum, const float* __restrict__ sqs,
                        const float* __restrict__ bn_ge,
                        const float* __restrict__ bn_gd,
                        const float* __restrict__ conve,
                        const float* __restrict__ convd,
                        float* __restrict__ alpha) {
    int tid = threadIdx.x;
    if (tid >= 384) return;
    float mean = sum[tid] * (1.0f / N1);
    float var  = sqs[tid] * (1.0f / N1) - mean * mean;
    float inv  = rsqrtf(fmaxf(var, 0.f) + EPSB);
    float g, cw, sgn;
    if (tid < 192) { g = bn_ge[tid];       cw = conve[tid];       sgn = -1.f; }
    else           { g = bn_gd[tid - 192]; cw = convd[tid - 192]; sgn =  1.f; }
    // ln2 folded so pass 2 can use __log2f directly
    alpha[tid] = sgn * cw * g * inv * INV_BETA * LN2;
}

__global__ __launch_bounds__(256, 7) void k_reduce_c(
    const float* __restrict__ x, const float* __restrict__ wg,
    const float* __restrict__ alpha, float* __restrict__ ye, float* __restrict__ yd) {
    __shared__ float EX[PLANE], EY[PLANE];
    const int tid = threadIdx.x;
    const int t = blockIdx.x;             // 18 tiles
    const int bz = blockIdx.y;            // b*8 + chunk
    const int b = bz >> 3, chunk = bz & 7;
    const int h0 = (t / NTW) * TILE_H, w0 = (t % NTW) * TILE_W;
    const int px = (tid & 31) + HALO;
    const int py0 = (tid >> 5) * 8;
    float accE[8] = {0,0,0,0,0,0,0,0}, accD[8] = {0,0,0,0,0,0,0,0};

    for (int ci = 0; ci < 8; ++ci) {
        const int c = chunk * 8 + ci;
        __syncthreads();
        load_tile(x + (size_t)(b * 64 + c) * HWn, EX, EY, h0, w0, tid);
        __syncthreads();

#define DO_SIDE_ACC(D, PL, SLOT, ACC) { \
        float S[8]; \
        sweep<D>(PL, py0, px, wg + (SLOT)*576 + c*9, S); \
        const float a_ = alpha[(SLOT)*64 + c]; \
        _Pragma("unroll") \
        for (int k = 0; k < 8; ++k) \
            ACC[k] = fmaf(a_, __log2f(fmaxf(S[k], SFLOOR)), ACC[k]); }

        DO_SIDE_ACC(1, EX, 0, accE)
        DO_SIDE_ACC(1, EY, 3, accD)
        DO_SIDE_ACC(2, EX, 1, accE)
        DO_SIDE_ACC(2, EY, 4, accD)
        DO_SIDE_ACC(3, EX, 2, accE)
        DO_SIDE_ACC(3, EY, 5, accD)
    }
#pragma unroll
    for (int k = 0; k < 8; ++k) {
        int idx = b * HWn + (h0 + py0 + k) * Wn + (w0 + px - HALO);
        atomicAdd(&ye[idx], accE[k]);
        atomicAdd(&yd[idx], accD[k]);
    }
}

__global__ __launch_bounds__(256) void k_fstats(const float* __restrict__ ye,
                                                const float* __restrict__ yd,
                                                float* __restrict__ scal) {
    int i = blockIdx.x * 256 + threadIdx.x;
    float a = ye[i], b = yd[i];
    float v[4] = {a, a * a, b, b * b};
    __shared__ float red[4][4];
    int lane = threadIdx.x & 63, wv = threadIdx.x >> 6;
#pragma unroll
    for (int k = 0; k < 4; ++k) {
        float tv = v[k];
#pragma unroll
        for (int off = 32; off; off >>= 1) tv += __shfl_down(tv, off, 64);
        if (lane == 0) red[wv][k] = tv;
    }
    __syncthreads();
    if (threadIdx.x < 4)
        atomicAdd(&scal[threadIdx.x],
                  red[0][threadIdx.x] + red[1][threadIdx.x] + red[2][threadIdx.x] + red[3][threadIdx.x]);
}

__global__ __launch_bounds__(256) void k_final(
    const float* __restrict__ ye, const float* __restrict__ yd,
    const float* __restrict__ scal,
    const float* __restrict__ g_e, const float* __restrict__ b_e,
    const float* __restrict__ g_d, const float* __restrict__ b_d,
    float* __restrict__ out) {
    int i = blockIdx.x * 256 + threadIdx.x;  // < 294912
    float me_ = scal[0] * (1.0f / N1);
    float ve  = scal[1] * (1.0f / N1) - me_ * me_;
    float ie  = rsqrtf(fmaxf(ve, 0.f) + EPSB);
    float md_ = scal[2] * (1.0f / N1);
    float vd  = scal[3] * (1.0f / N1) - md_ * md_;
    float idv = rsqrtf(fmaxf(vd, 0.f) + EPSB);
    float ge = g_e[0], be = b_e[0];
    float gd = g_d[0], bd = b_d[0];
    int b = i / HWn, rem = i - b * HWn;
    float oe = fmaxf(ge * (ye[i] - me_) * ie + be, 0.f);
    float od = fmaxf(gd * (yd[i] - md_) * idv + bd, 0.f);
    out[(size_t)(b * 2) * HWn + rem]     = oe;
    out[(size_t)(b * 2 + 1) * HWn + rem] = od;
}

extern "C" void kernel_launch(void* const* d_in, const int* in_sizes, int n_in,
                              void* d_out, int out_size, void* d_ws, size_t ws_size,
                              hipStream_t stream) {
    const float* x     = (const float*)d_in[0];
    const float* we    = (const float*)d_in[1];
    const float* wd    = (const float*)d_in[2];
    const float* bn_ge = (const float*)d_in[3];
    const float* bn_gd = (const float*)d_in[5];
    const float* conve = (const float*)d_in[7];
    const float* convd = (const float*)d_in[8];
    const float* g_e   = (const float*)d_in[9];
    const float* b_e   = (const float*)d_in[10];
    const float* g_d   = (const float*)d_in[11];
    const float* b_d   = (const float*)d_in[12];
    float* ws = (float*)d_ws;

    hipMemsetAsync(d_ws, 0, (size_t)WS_TOTAL * sizeof(float), stream);
    hipLaunchKernelGGL(k_wexp, dim3(14), dim3(256), 0, stream, we, wd, ws + WS_WG);
    hipLaunchKernelGGL(k_morph_stats, dim3(NTILES, 512), dim3(256), 0, stream,
                       x, ws + WS_WG, ws + WS_SUM, ws + WS_SQS);
    hipLaunchKernelGGL(k_alpha, dim3(1), dim3(384), 0, stream,
                       ws + WS_SUM, ws + WS_SQS, bn_ge, bn_gd, conve, convd, ws + WS_ALPHA);
    hipLaunchKernelGGL(k_reduce_c, dim3(NTILES, 64), dim3(256), 0, stream,
                       x, ws + WS_WG, ws + WS_ALPHA, ws + WS_YE, ws + WS_YD);
    hipLaunchKernelGGL(k_fstats, dim3(1152), dim3(256), 0, stream,
                       ws + WS_YE, ws + WS_YD, ws + WS_SCAL);
    hipLaunchKernelGGL(k_final, dim3(1152), dim3(256), 0, stream,
                       ws + WS_YE, ws + WS_YD, ws + WS_SCAL, g_e, b_e, g_d, b_d,
                       (float*)d_out);
}